// Round 1
// baseline (1137.105 us; speedup 1.0000x reference)
//
#include <hip/hip_runtime.h>
#include <hip/hip_bf16.h>

#define N_NODES 65536
#define B_G     64
#define NPG     1024
#define KC      128
#define DIN     128
#define DOUT    128
#define E_EDGES 1048576
#define EPG     16384

typedef __attribute__((ext_vector_type(8))) short short8;
typedef __attribute__((ext_vector_type(4))) float floatx4;

static __device__ __forceinline__ short f2bf(float x) {
    unsigned u = __float_as_uint(x);
    unsigned r = (u + 0x7FFF + ((u >> 16) & 1)) >> 16;
    return (short)r;
}

// ---------------- prep: W -> Wt bf16 [n][k0..255], fea -> feaT bf16 [g][d][k]
__global__ __launch_bounds__(256) void prep_kernel(
    const float* __restrict__ Wself, const float* __restrict__ Wneigh,
    const float* __restrict__ fea, short* __restrict__ wt, short* __restrict__ feaT)
{
    int idx = blockIdx.x * 256 + threadIdx.x;
    if (idx < 128 * 256) {
        int n = idx >> 8, k = idx & 255;
        float v = (k < 128) ? Wself[k * 128 + n] : Wneigh[(k - 128) * 128 + n];
        wt[idx] = f2bf(v);
    }
    int fidx = idx - 128 * 256;
    if (fidx >= 0 && fidx < B_G * 128 * 128) {
        int g = fidx >> 14;
        int d = (fidx >> 7) & 127;
        int k = fidx & 127;
        feaT[fidx] = f2bf(fea[(g * KC + k) * DOUT + d]);
    }
}

// ---------------- aggregation: neigh sums (bf16) + deg (f32)
// grid = 64 graphs * 9 (8 feature chunks of 16 + 1 degree pass)
__global__ __launch_bounds__(256) void agg_kernel(
    const float* __restrict__ h, const int* __restrict__ esrc,
    const int* __restrict__ edst, short* __restrict__ neigh, float* __restrict__ deg)
{
    __shared__ float acc[NPG * 16];   // 64 KB
    int g = blockIdx.x / 9;
    int c = blockIdx.x % 9;
    int tid = threadIdx.x;
    int nodebase = g * NPG;
    int ebase = g * EPG;
    if (c < 8) {
        for (int i = tid; i < NPG * 16; i += 256) acc[i] = 0.f;
        __syncthreads();
        int j = tid & 15;
        int grp = tid >> 4;          // 16 edges in parallel
        int fb = c * 16 + j;
        for (int e = grp; e < EPG; e += 16) {
            int s = esrc[ebase + e];
            int d = edst[ebase + e];
            float v = h[(size_t)s * DIN + fb];
            atomicAdd(&acc[((d - nodebase) << 4) + j], v);
        }
        __syncthreads();
        for (int i = tid; i < NPG * 16; i += 256) {
            int node = i >> 4, f = i & 15;
            neigh[(size_t)(nodebase + node) * DIN + c * 16 + f] = f2bf(acc[i]);
        }
    } else {
        for (int i = tid; i < NPG; i += 256) acc[i] = 0.f;
        __syncthreads();
        for (int e = tid; e < EPG; e += 256) {
            int d = edst[ebase + e];
            atomicAdd(&acc[d - nodebase], 1.f);
        }
        __syncthreads();
        for (int i = tid; i < NPG; i += 256) deg[nodebase + i] = acc[i];
    }
}

// ---------------- assign = softmax(relu([h | neigh/deg] @ Wt^T + b)), bf16 out
// one WG per 128 rows; 4 waves, each 32 rows x 128 cols; K=256 in 4 chunks of 64
__global__ __launch_bounds__(256) void assign_kernel(
    const float* __restrict__ h, const short* __restrict__ neigh,
    const float* __restrict__ deg, const short* __restrict__ wt,
    const float* __restrict__ bias, short* __restrict__ assign_out)
{
    __shared__ short lds_a[128 * 72];
    __shared__ short lds_b[128 * 72];
    int tid = threadIdx.x;
    int tile_m = blockIdx.x * 128;
    int wave = tid >> 6, lane = tid & 63;
    int l15 = lane & 15, quad = lane >> 4;

    floatx4 zz = {0.f, 0.f, 0.f, 0.f};
    floatx4 acc[2][8];
#pragma unroll
    for (int i = 0; i < 2; i++)
#pragma unroll
        for (int j = 0; j < 8; j++) acc[i][j] = zz;

    int row_s = tid >> 1;
    int c0 = (tid & 1) * 32;
    float invd = 1.0f / fmaxf(deg[tile_m + row_s], 1.0f);

    for (int kk = 0; kk < 4; kk++) {
        // stage A chunk: cols kk*64 .. kk*64+63 of [h | neigh/deg]
        short* dsta = lds_a + row_s * 72 + c0;
        if (kk < 2) {
            const float* src = h + (size_t)(tile_m + row_s) * DIN + kk * 64 + c0;
#pragma unroll
            for (int i = 0; i < 32; i += 4) {
                float4 v = *reinterpret_cast<const float4*>(src + i);
                dsta[i + 0] = f2bf(v.x); dsta[i + 1] = f2bf(v.y);
                dsta[i + 2] = f2bf(v.z); dsta[i + 3] = f2bf(v.w);
            }
        } else {
            const short* src = neigh + (size_t)(tile_m + row_s) * DIN + (kk - 2) * 64 + c0;
#pragma unroll
            for (int i = 0; i < 32; i += 8) {
                short8 v = *reinterpret_cast<const short8*>(src + i);
#pragma unroll
                for (int u = 0; u < 8; u++) {
                    float f = __uint_as_float(((unsigned)(unsigned short)v[u]) << 16);
                    dsta[i + u] = f2bf(f * invd);
                }
            }
        }
        // stage B chunk from wt [n][256]
        {
            const short* src = wt + row_s * 256 + kk * 64 + c0;
            short* dst = lds_b + row_s * 72 + c0;
#pragma unroll
            for (int i = 0; i < 32; i += 8)
                *reinterpret_cast<short8*>(dst + i) = *reinterpret_cast<const short8*>(src + i);
        }
        __syncthreads();
#pragma unroll
        for (int ks = 0; ks < 2; ks++) {
            short8 af[2];
#pragma unroll
            for (int rb = 0; rb < 2; rb++) {
                int m = wave * 32 + rb * 16 + l15;
                af[rb] = *reinterpret_cast<const short8*>(lds_a + m * 72 + ks * 32 + quad * 8);
            }
#pragma unroll
            for (int cb = 0; cb < 8; cb++) {
                int n = cb * 16 + l15;
                short8 bf = *reinterpret_cast<const short8*>(lds_b + n * 72 + ks * 32 + quad * 8);
                acc[0][cb] = __builtin_amdgcn_mfma_f32_16x16x32_bf16(af[0], bf, acc[0][cb], 0, 0, 0);
                acc[1][cb] = __builtin_amdgcn_mfma_f32_16x16x32_bf16(af[1], bf, acc[1][cb], 0, 0, 0);
            }
        }
        __syncthreads();
    }

    // epilogue: +bias, relu, softmax over 128 cols, write bf16
    float bv[8];
#pragma unroll
    for (int cb = 0; cb < 8; cb++) bv[cb] = bias[cb * 16 + l15];

#pragma unroll
    for (int rb = 0; rb < 2; rb++) {
#pragma unroll
        for (int v = 0; v < 4; v++) {
            float x[8];
            float m = -1e30f;
#pragma unroll
            for (int cb = 0; cb < 8; cb++) {
                float t = acc[rb][cb][v] + bv[cb];
                t = fmaxf(t, 0.f);
                x[cb] = t;
                m = fmaxf(m, t);
            }
#pragma unroll
            for (int off = 1; off < 16; off <<= 1) m = fmaxf(m, __shfl_xor(m, off, 64));
            float s = 0.f;
#pragma unroll
            for (int cb = 0; cb < 8; cb++) { x[cb] = __expf(x[cb] - m); s += x[cb]; }
#pragma unroll
            for (int off = 1; off < 16; off <<= 1) s += __shfl_xor(s, off, 64);
            float inv = 1.0f / s;
            int row = tile_m + wave * 32 + rb * 16 + quad * 4 + v;
#pragma unroll
            for (int cb = 0; cb < 8; cb++)
                assign_out[(size_t)row * KC + cb * 16 + l15] = f2bf(x[cb] * inv);
        }
    }
}

// ---------------- out = per-graph assign @ fea  (bf16 MFMA, fp32 out)
__global__ __launch_bounds__(256) void out_kernel(
    const short* __restrict__ assign_in, const short* __restrict__ feaT,
    float* __restrict__ out)
{
    __shared__ short lds_a[128 * 72];
    __shared__ short lds_b[128 * 72];
    int tid = threadIdx.x;
    int tile_m = blockIdx.x * 128;
    int g = tile_m >> 10;
    int wave = tid >> 6, lane = tid & 63;
    int l15 = lane & 15, quad = lane >> 4;

    floatx4 zz = {0.f, 0.f, 0.f, 0.f};
    floatx4 acc[2][8];
#pragma unroll
    for (int i = 0; i < 2; i++)
#pragma unroll
        for (int j = 0; j < 8; j++) acc[i][j] = zz;

    int row_s = tid >> 1;
    int c0 = (tid & 1) * 32;

    for (int kk = 0; kk < 2; kk++) {
        const short* srca = assign_in + (size_t)(tile_m + row_s) * KC + kk * 64 + c0;
        short* dsta = lds_a + row_s * 72 + c0;
#pragma unroll
        for (int i = 0; i < 32; i += 8)
            *reinterpret_cast<short8*>(dsta + i) = *reinterpret_cast<const short8*>(srca + i);
        const short* srcb = feaT + ((size_t)g * 128 + row_s) * KC + kk * 64 + c0;
        short* dstb = lds_b + row_s * 72 + c0;
#pragma unroll
        for (int i = 0; i < 32; i += 8)
            *reinterpret_cast<short8*>(dstb + i) = *reinterpret_cast<const short8*>(srcb + i);
        __syncthreads();
#pragma unroll
        for (int ks = 0; ks < 2; ks++) {
            short8 af[2];
#pragma unroll
            for (int rb = 0; rb < 2; rb++) {
                int m = wave * 32 + rb * 16 + l15;
                af[rb] = *reinterpret_cast<const short8*>(lds_a + m * 72 + ks * 32 + quad * 8);
            }
#pragma unroll
            for (int cb = 0; cb < 8; cb++) {
                int n = cb * 16 + l15;
                short8 bf = *reinterpret_cast<const short8*>(lds_b + n * 72 + ks * 32 + quad * 8);
                acc[0][cb] = __builtin_amdgcn_mfma_f32_16x16x32_bf16(af[0], bf, acc[0][cb], 0, 0, 0);
                acc[1][cb] = __builtin_amdgcn_mfma_f32_16x16x32_bf16(af[1], bf, acc[1][cb], 0, 0, 0);
            }
        }
        __syncthreads();
    }

#pragma unroll
    for (int rb = 0; rb < 2; rb++)
#pragma unroll
        for (int v = 0; v < 4; v++) {
            int row = tile_m + wave * 32 + rb * 16 + quad * 4 + v;
#pragma unroll
            for (int cb = 0; cb < 8; cb++)
                out[(size_t)row * DOUT + cb * 16 + l15] = acc[rb][cb][v];
        }
}

extern "C" void kernel_launch(void* const* d_in, const int* in_sizes, int n_in,
                              void* d_out, int out_size, void* d_ws, size_t ws_size,
                              hipStream_t stream) {
    const float* h      = (const float*)d_in[0];
    const float* fea    = (const float*)d_in[1];
    const float* Wself  = (const float*)d_in[2];
    const float* Wneigh = (const float*)d_in[3];
    const float* bias   = (const float*)d_in[4];
    const int*   esrc   = (const int*)d_in[5];
    const int*   edst   = (const int*)d_in[6];
    float* out = (float*)d_out;

    char* ws = (char*)d_ws;
    short* neigh  = (short*)ws;                                   // 16 MB bf16 sums
    size_t off = (size_t)N_NODES * DIN * sizeof(short);
    float* deg    = (float*)(ws + off);  off += (size_t)N_NODES * sizeof(float);   // 256 KB
    short* assign = (short*)(ws + off);  off += (size_t)N_NODES * KC * sizeof(short); // 16 MB
    short* wt     = (short*)(ws + off);  off += (size_t)128 * 256 * sizeof(short);    // 64 KB
    short* feaT   = (short*)(ws + off);                           // 2 MB

    prep_kernel<<<4224, 256, 0, stream>>>(Wself, Wneigh, fea, wt, feaT);
    agg_kernel<<<B_G * 9, 256, 0, stream>>>(h, esrc, edst, neigh, deg);
    assign_kernel<<<N_NODES / 128, 256, 0, stream>>>(h, neigh, deg, wt, bias, assign);
    out_kernel<<<N_NODES / 128, 256, 0, stream>>>(assign, feaT, out);
}

// Round 2
// 820.213 us; speedup vs baseline: 1.3864x; 1.3864x over previous
//
#include <hip/hip_runtime.h>
#include <hip/hip_bf16.h>

#define N_NODES 65536
#define B_G     64
#define NPG     1024
#define KC      128
#define DIN     128
#define DOUT    128
#define E_EDGES 1048576
#define EPG     16384

typedef __attribute__((ext_vector_type(8))) short short8;
typedef __attribute__((ext_vector_type(4))) float floatx4;

static __device__ __forceinline__ short f2bf(float x) {
    unsigned u = __float_as_uint(x);
    unsigned r = (u + 0x7FFF + ((u >> 16) & 1)) >> 16;
    return (short)r;
}

// ---------------- prep: W -> Wt bf16 [n][256], fea -> feaT bf16 [g][d][k],
//                   edges -> pack[e] = s_local | (d_local<<16)
__global__ __launch_bounds__(256) void prep_kernel(
    const float* __restrict__ Wself, const float* __restrict__ Wneigh,
    const float* __restrict__ fea, const int* __restrict__ esrc,
    const int* __restrict__ edst, short* __restrict__ wt,
    short* __restrict__ feaT, int* __restrict__ pack)
{
    int idx = blockIdx.x * 256 + threadIdx.x;
    if (idx < 128 * 256) {
        int n = idx >> 8, k = idx & 255;
        float v = (k < 128) ? Wself[k * 128 + n] : Wneigh[(k - 128) * 128 + n];
        wt[idx] = f2bf(v);
    } else if (idx < 128 * 256 + B_G * 128 * 128) {
        int fidx = idx - 128 * 256;
        int g = fidx >> 14;
        int d = (fidx >> 7) & 127;
        int k = fidx & 127;
        feaT[fidx] = f2bf(fea[(g * KC + k) * DOUT + d]);
    } else if (idx < 128 * 256 + B_G * 128 * 128 + E_EDGES) {
        int e = idx - (128 * 256 + B_G * 128 * 128);
        int base = (e >> 14) << 10;               // graph base node
        int s = esrc[e] - base;
        int d = edst[e] - base;
        pack[e] = s | (d << 16);
    }
}

// ---------------- degree: one block per graph, LDS histogram
__global__ __launch_bounds__(256) void deg_kernel(
    const int* __restrict__ pack, float* __restrict__ deg)
{
    __shared__ float dacc[NPG];
    int g = blockIdx.x;
    int tid = threadIdx.x;
    for (int i = tid; i < NPG; i += 256) dacc[i] = 0.f;
    __syncthreads();
    const int* pk = pack + g * EPG;
#pragma unroll 8
    for (int it = 0; it < EPG / 256; it++) {
        int d = ((unsigned)pk[it * 256 + tid]) >> 16;
        atomicAdd(&dacc[d], 1.f);
    }
    __syncthreads();
    for (int i = tid; i < NPG; i += 256) deg[g * NPG + i] = dacc[i];
}

// ---------------- aggregation: blockIdx = c*64 + g  (c = 16-feature chunk)
// 512 threads, 64 KB LDS acc; unroll-8 pipelined gather; writes bf16 neigh/deg
__global__ __launch_bounds__(512) void agg_kernel(
    const float* __restrict__ h, const int* __restrict__ pack,
    const float* __restrict__ deg, short* __restrict__ neigh)
{
    __shared__ float acc[NPG * 16];   // 64 KB
    int g = blockIdx.x & 63;
    int c = blockIdx.x >> 6;
    int tid = threadIdx.x;
    for (int i = tid; i < NPG * 16; i += 512) acc[i] = 0.f;
    __syncthreads();

    int j = tid & 15;            // feature within chunk
    int grp = tid >> 4;          // 32 edges in parallel
    int fb = c * 16 + j;
    const int* pk = pack + g * EPG;
    const float* hg = h + ((size_t)g << 10) * DIN + fb;

    for (int it0 = 0; it0 < EPG / 32; it0 += 8) {
        int pk8[8];
#pragma unroll
        for (int u = 0; u < 8; u++) pk8[u] = pk[(it0 + u) * 32 + grp];
        float v[8];
#pragma unroll
        for (int u = 0; u < 8; u++) {
            int s = pk8[u] & 0xFFFF;
            v[u] = hg[(size_t)s * DIN];
        }
#pragma unroll
        for (int u = 0; u < 8; u++) {
            int d = ((unsigned)pk8[u]) >> 16;
            atomicAdd(&acc[(d << 4) + j], v[u]);
        }
    }
    __syncthreads();

    int nodebase = g * NPG;
    for (int i = tid; i < NPG * 16; i += 512) {
        int node = i >> 4, f = i & 15;
        float invd = 1.0f / fmaxf(deg[nodebase + node], 1.0f);
        neigh[(size_t)(nodebase + node) * DIN + c * 16 + f] = f2bf(acc[i] * invd);
    }
}

// ---------------- assign = softmax(relu([h | neigh] @ Wt^T + b)), bf16 out
__global__ __launch_bounds__(256) void assign_kernel(
    const float* __restrict__ h, const short* __restrict__ neigh,
    const short* __restrict__ wt, const float* __restrict__ bias,
    short* __restrict__ assign_out)
{
    __shared__ short lds_a[128 * 72];
    __shared__ short lds_b[128 * 72];
    int tid = threadIdx.x;
    int tile_m = blockIdx.x * 128;
    int wave = tid >> 6, lane = tid & 63;
    int l15 = lane & 15, quad = lane >> 4;

    floatx4 zz = {0.f, 0.f, 0.f, 0.f};
    floatx4 acc[2][8];
#pragma unroll
    for (int i = 0; i < 2; i++)
#pragma unroll
        for (int j = 0; j < 8; j++) acc[i][j] = zz;

    int row_s = tid >> 1;
    int c0 = (tid & 1) * 32;

    for (int kk = 0; kk < 4; kk++) {
        short* dsta = lds_a + row_s * 72 + c0;
        if (kk < 2) {
            const float* src = h + (size_t)(tile_m + row_s) * DIN + kk * 64 + c0;
#pragma unroll
            for (int i = 0; i < 32; i += 4) {
                float4 v = *reinterpret_cast<const float4*>(src + i);
                dsta[i + 0] = f2bf(v.x); dsta[i + 1] = f2bf(v.y);
                dsta[i + 2] = f2bf(v.z); dsta[i + 3] = f2bf(v.w);
            }
        } else {
            const short* src = neigh + (size_t)(tile_m + row_s) * DIN + (kk - 2) * 64 + c0;
#pragma unroll
            for (int i = 0; i < 32; i += 8)
                *reinterpret_cast<short8*>(dsta + i) = *reinterpret_cast<const short8*>(src + i);
        }
        {
            const short* src = wt + row_s * 256 + kk * 64 + c0;
            short* dst = lds_b + row_s * 72 + c0;
#pragma unroll
            for (int i = 0; i < 32; i += 8)
                *reinterpret_cast<short8*>(dst + i) = *reinterpret_cast<const short8*>(src + i);
        }
        __syncthreads();
#pragma unroll
        for (int ks = 0; ks < 2; ks++) {
            short8 af[2];
#pragma unroll
            for (int rb = 0; rb < 2; rb++) {
                int m = wave * 32 + rb * 16 + l15;
                af[rb] = *reinterpret_cast<const short8*>(lds_a + m * 72 + ks * 32 + quad * 8);
            }
#pragma unroll
            for (int cb = 0; cb < 8; cb++) {
                int n = cb * 16 + l15;
                short8 bf = *reinterpret_cast<const short8*>(lds_b + n * 72 + ks * 32 + quad * 8);
                acc[0][cb] = __builtin_amdgcn_mfma_f32_16x16x32_bf16(af[0], bf, acc[0][cb], 0, 0, 0);
                acc[1][cb] = __builtin_amdgcn_mfma_f32_16x16x32_bf16(af[1], bf, acc[1][cb], 0, 0, 0);
            }
        }
        __syncthreads();
    }

    float bv[8];
#pragma unroll
    for (int cb = 0; cb < 8; cb++) bv[cb] = bias[cb * 16 + l15];

#pragma unroll
    for (int rb = 0; rb < 2; rb++) {
#pragma unroll
        for (int v = 0; v < 4; v++) {
            float x[8];
            float m = -1e30f;
#pragma unroll
            for (int cb = 0; cb < 8; cb++) {
                float t = acc[rb][cb][v] + bv[cb];
                t = fmaxf(t, 0.f);
                x[cb] = t;
                m = fmaxf(m, t);
            }
#pragma unroll
            for (int off = 1; off < 16; off <<= 1) m = fmaxf(m, __shfl_xor(m, off, 64));
            float s = 0.f;
#pragma unroll
            for (int cb = 0; cb < 8; cb++) { x[cb] = __expf(x[cb] - m); s += x[cb]; }
#pragma unroll
            for (int off = 1; off < 16; off <<= 1) s += __shfl_xor(s, off, 64);
            float inv = 1.0f / s;
            int row = tile_m + wave * 32 + rb * 16 + quad * 4 + v;
#pragma unroll
            for (int cb = 0; cb < 8; cb++)
                assign_out[(size_t)row * KC + cb * 16 + l15] = f2bf(x[cb] * inv);
        }
    }
}

// ---------------- out = per-graph assign @ fea  (bf16 MFMA, fp32 out)
__global__ __launch_bounds__(256) void out_kernel(
    const short* __restrict__ assign_in, const short* __restrict__ feaT,
    float* __restrict__ out)
{
    __shared__ short lds_a[128 * 72];
    __shared__ short lds_b[128 * 72];
    int tid = threadIdx.x;
    int tile_m = blockIdx.x * 128;
    int g = tile_m >> 10;
    int wave = tid >> 6, lane = tid & 63;
    int l15 = lane & 15, quad = lane >> 4;

    floatx4 zz = {0.f, 0.f, 0.f, 0.f};
    floatx4 acc[2][8];
#pragma unroll
    for (int i = 0; i < 2; i++)
#pragma unroll
        for (int j = 0; j < 8; j++) acc[i][j] = zz;

    int row_s = tid >> 1;
    int c0 = (tid & 1) * 32;

    for (int kk = 0; kk < 2; kk++) {
        const short* srca = assign_in + (size_t)(tile_m + row_s) * KC + kk * 64 + c0;
        short* dsta = lds_a + row_s * 72 + c0;
#pragma unroll
        for (int i = 0; i < 32; i += 8)
            *reinterpret_cast<short8*>(dsta + i) = *reinterpret_cast<const short8*>(srca + i);
        const short* srcb = feaT + ((size_t)g * 128 + row_s) * KC + kk * 64 + c0;
        short* dstb = lds_b + row_s * 72 + c0;
#pragma unroll
        for (int i = 0; i < 32; i += 8)
            *reinterpret_cast<short8*>(dstb + i) = *reinterpret_cast<const short8*>(srcb + i);
        __syncthreads();
#pragma unroll
        for (int ks = 0; ks < 2; ks++) {
            short8 af[2];
#pragma unroll
            for (int rb = 0; rb < 2; rb++) {
                int m = wave * 32 + rb * 16 + l15;
                af[rb] = *reinterpret_cast<const short8*>(lds_a + m * 72 + ks * 32 + quad * 8);
            }
#pragma unroll
            for (int cb = 0; cb < 8; cb++) {
                int n = cb * 16 + l15;
                short8 bf = *reinterpret_cast<const short8*>(lds_b + n * 72 + ks * 32 + quad * 8);
                acc[0][cb] = __builtin_amdgcn_mfma_f32_16x16x32_bf16(af[0], bf, acc[0][cb], 0, 0, 0);
                acc[1][cb] = __builtin_amdgcn_mfma_f32_16x16x32_bf16(af[1], bf, acc[1][cb], 0, 0, 0);
            }
        }
        __syncthreads();
    }

#pragma unroll
    for (int rb = 0; rb < 2; rb++)
#pragma unroll
        for (int v = 0; v < 4; v++) {
            int row = tile_m + wave * 32 + rb * 16 + quad * 4 + v;
#pragma unroll
            for (int cb = 0; cb < 8; cb++)
                out[(size_t)row * DOUT + cb * 16 + l15] = acc[rb][cb][v];
        }
}

extern "C" void kernel_launch(void* const* d_in, const int* in_sizes, int n_in,
                              void* d_out, int out_size, void* d_ws, size_t ws_size,
                              hipStream_t stream) {
    const float* h      = (const float*)d_in[0];
    const float* fea    = (const float*)d_in[1];
    const float* Wself  = (const float*)d_in[2];
    const float* Wneigh = (const float*)d_in[3];
    const float* bias   = (const float*)d_in[4];
    const int*   esrc   = (const int*)d_in[5];
    const int*   edst   = (const int*)d_in[6];
    float* out = (float*)d_out;

    char* ws = (char*)d_ws;
    short* neigh  = (short*)ws;                                   // 16 MB bf16 (pre-divided)
    size_t off = (size_t)N_NODES * DIN * sizeof(short);
    float* deg    = (float*)(ws + off);  off += (size_t)N_NODES * sizeof(float);      // 256 KB
    short* assign = (short*)(ws + off);  off += (size_t)N_NODES * KC * sizeof(short); // 16 MB
    short* wt     = (short*)(ws + off);  off += (size_t)128 * 256 * sizeof(short);    // 64 KB
    short* feaT   = (short*)(ws + off);  off += (size_t)B_G * 128 * 128 * sizeof(short); // 2 MB
    int*   pack   = (int*)(ws + off);                             // 4 MB

    int prep_total = 128 * 256 + B_G * 128 * 128 + E_EDGES;
    prep_kernel<<<(prep_total + 255) / 256, 256, 0, stream>>>(Wself, Wneigh, fea, esrc, edst, wt, feaT, pack);
    deg_kernel<<<B_G, 256, 0, stream>>>(pack, deg);
    agg_kernel<<<8 * B_G, 512, 0, stream>>>(h, pack, deg, neigh);
    assign_kernel<<<N_NODES / 128, 256, 0, stream>>>(h, neigh, wt, bias, assign);
    out_kernel<<<N_NODES / 128, 256, 0, stream>>>(assign, feaT, out);
}

// Round 3
// 194.914 us; speedup vs baseline: 5.8339x; 4.2081x over previous
//
#include <hip/hip_runtime.h>
#include <hip/hip_bf16.h>

#define N_NODES 65536
#define B_G     64
#define NPG     1024
#define KC      128
#define DIN     128
#define DOUT    128
#define E_EDGES 1048576
#define EPG     16384

typedef __attribute__((ext_vector_type(8))) short short8;
typedef __attribute__((ext_vector_type(4))) float floatx4;

static __device__ __forceinline__ short f2bf(float x) {
    unsigned u = __float_as_uint(x);
    unsigned r = (u + 0x7FFF + ((u >> 16) & 1)) >> 16;
    return (short)r;
}

// ---------------- prep: W -> Wt bf16 [n][256], fea -> feaT bf16 [g][d][k],
//                   edges -> pack[e] = s_local | (d_local<<16)
__global__ __launch_bounds__(256) void prep_kernel(
    const float* __restrict__ Wself, const float* __restrict__ Wneigh,
    const float* __restrict__ fea, const int* __restrict__ esrc,
    const int* __restrict__ edst, short* __restrict__ wt,
    short* __restrict__ feaT, int* __restrict__ pack)
{
    int idx = blockIdx.x * 256 + threadIdx.x;
    if (idx < 128 * 256) {
        int n = idx >> 8, k = idx & 255;
        float v = (k < 128) ? Wself[k * 128 + n] : Wneigh[(k - 128) * 128 + n];
        wt[idx] = f2bf(v);
    } else if (idx < 128 * 256 + B_G * 128 * 128) {
        int fidx = idx - 128 * 256;
        int g = fidx >> 14;
        int d = (fidx >> 7) & 127;
        int k = fidx & 127;
        feaT[fidx] = f2bf(fea[(g * KC + k) * DOUT + d]);
    } else if (idx < 128 * 256 + B_G * 128 * 128 + E_EDGES) {
        int e = idx - (128 * 256 + B_G * 128 * 128);
        int base = (e >> 14) << 10;               // graph base node
        int s = esrc[e] - base;
        int d = edst[e] - base;
        pack[e] = s | (d << 16);
    }
}

// ---------------- CSR build: one block per graph, 1024 threads
// count (LDS int atomics) -> prefix scan -> scatter src ids (ushort)
__global__ __launch_bounds__(1024) void csr_kernel(
    const int* __restrict__ pack, unsigned short* __restrict__ csr,
    int* __restrict__ offs)
{
    __shared__ int cnt[NPG];
    __shared__ int sa[NPG];
    __shared__ int sb[NPG];
    int g = blockIdx.x;
    int tid = threadIdx.x;
    cnt[tid] = 0;
    __syncthreads();
    const int* pk = pack + (size_t)g * EPG;
    int pe[16];
#pragma unroll
    for (int it = 0; it < 16; it++) pe[it] = pk[it * 1024 + tid];
#pragma unroll
    for (int it = 0; it < 16; it++)
        atomicAdd(&cnt[((unsigned)pe[it]) >> 16], 1);
    __syncthreads();
    // inclusive scan over 1024 degrees (Hillis-Steele, ping-pong)
    sa[tid] = cnt[tid];
    __syncthreads();
    int* src = sa; int* dst = sb;
    for (int off = 1; off < NPG; off <<= 1) {
        int v = src[tid];
        if (tid >= off) v += src[tid - off];
        dst[tid] = v;
        __syncthreads();
        int* t = src; src = dst; dst = t;
    }
    int excl = src[tid] - cnt[tid];
    offs[g * NPG + tid] = excl;
    cnt[tid] = excl;      // reuse cnt[] as scatter cursor
    __syncthreads();
    unsigned short* cg = csr + (size_t)g * EPG;
#pragma unroll
    for (int it = 0; it < 16; it++) {
        int d = ((unsigned)pe[it]) >> 16;
        int s = pe[it] & 0xFFFF;
        int pos = atomicAdd(&cnt[d], 1);
        cg[pos] = (unsigned short)s;
    }
}

// ---------------- aggregation (pull): one wave per node, 64 lanes = row (float2)
// blockIdx = chunk*64 + g  (keeps graph g's traffic on XCD g%8)
__global__ __launch_bounds__(256) void agg_kernel(
    const float* __restrict__ h, const unsigned short* __restrict__ csr,
    const int* __restrict__ offs, short* __restrict__ neigh)
{
    int g = blockIdx.x & 63;
    int chunk = blockIdx.x >> 6;
    int wave = threadIdx.x >> 6, lane = threadIdx.x & 63;
    int local = chunk * 4 + wave;
    int start = offs[g * NPG + local];
    int end = (local < NPG - 1) ? offs[g * NPG + local + 1] : EPG;
    int m = end - start;
    const unsigned short* lst = csr + (size_t)g * EPG + start;
    const float2* h2 = (const float2*)h + (size_t)(g * NPG) * 64;
    float sx = 0.f, sy = 0.f;
    int n = 0;
    for (; n + 4 <= m; n += 4) {
        int s0 = lst[n], s1 = lst[n + 1], s2 = lst[n + 2], s3 = lst[n + 3];
        float2 v0 = h2[s0 * 64 + lane];
        float2 v1 = h2[s1 * 64 + lane];
        float2 v2 = h2[s2 * 64 + lane];
        float2 v3 = h2[s3 * 64 + lane];
        sx += v0.x + v1.x + v2.x + v3.x;
        sy += v0.y + v1.y + v2.y + v3.y;
    }
    for (; n < m; n++) {
        float2 v = h2[lst[n] * 64 + lane];
        sx += v.x; sy += v.y;
    }
    float invd = 1.0f / fmaxf((float)m, 1.0f);
    unsigned lo = (unsigned)(unsigned short)f2bf(sx * invd);
    unsigned hi = (unsigned)(unsigned short)f2bf(sy * invd);
    ((unsigned*)neigh)[(size_t)(g * NPG + local) * 64 + lane] = lo | (hi << 16);
}

// ---------------- assign = softmax(relu([h | neigh] @ Wt^T + b)), bf16 out
__global__ __launch_bounds__(256) void assign_kernel(
    const float* __restrict__ h, const short* __restrict__ neigh,
    const short* __restrict__ wt, const float* __restrict__ bias,
    short* __restrict__ assign_out)
{
    __shared__ short lds_a[128 * 72];
    __shared__ short lds_b[128 * 72];
    int tid = threadIdx.x;
    int tile_m = blockIdx.x * 128;
    int wave = tid >> 6, lane = tid & 63;
    int l15 = lane & 15, quad = lane >> 4;

    floatx4 zz = {0.f, 0.f, 0.f, 0.f};
    floatx4 acc[2][8];
#pragma unroll
    for (int i = 0; i < 2; i++)
#pragma unroll
        for (int j = 0; j < 8; j++) acc[i][j] = zz;

    int row_s = tid >> 1;
    int c0 = (tid & 1) * 32;

    for (int kk = 0; kk < 4; kk++) {
        short* dsta = lds_a + row_s * 72 + c0;
        if (kk < 2) {
            const float* src = h + (size_t)(tile_m + row_s) * DIN + kk * 64 + c0;
#pragma unroll
            for (int i = 0; i < 32; i += 4) {
                float4 v = *reinterpret_cast<const float4*>(src + i);
                dsta[i + 0] = f2bf(v.x); dsta[i + 1] = f2bf(v.y);
                dsta[i + 2] = f2bf(v.z); dsta[i + 3] = f2bf(v.w);
            }
        } else {
            const short* src = neigh + (size_t)(tile_m + row_s) * DIN + (kk - 2) * 64 + c0;
#pragma unroll
            for (int i = 0; i < 32; i += 8)
                *reinterpret_cast<short8*>(dsta + i) = *reinterpret_cast<const short8*>(src + i);
        }
        {
            const short* src = wt + row_s * 256 + kk * 64 + c0;
            short* dst = lds_b + row_s * 72 + c0;
#pragma unroll
            for (int i = 0; i < 32; i += 8)
                *reinterpret_cast<short8*>(dst + i) = *reinterpret_cast<const short8*>(src + i);
        }
        __syncthreads();
#pragma unroll
        for (int ks = 0; ks < 2; ks++) {
            short8 af[2];
#pragma unroll
            for (int rb = 0; rb < 2; rb++) {
                int m = wave * 32 + rb * 16 + l15;
                af[rb] = *reinterpret_cast<const short8*>(lds_a + m * 72 + ks * 32 + quad * 8);
            }
#pragma unroll
            for (int cb = 0; cb < 8; cb++) {
                int n = cb * 16 + l15;
                short8 bf = *reinterpret_cast<const short8*>(lds_b + n * 72 + ks * 32 + quad * 8);
                acc[0][cb] = __builtin_amdgcn_mfma_f32_16x16x32_bf16(af[0], bf, acc[0][cb], 0, 0, 0);
                acc[1][cb] = __builtin_amdgcn_mfma_f32_16x16x32_bf16(af[1], bf, acc[1][cb], 0, 0, 0);
            }
        }
        __syncthreads();
    }

    float bv[8];
#pragma unroll
    for (int cb = 0; cb < 8; cb++) bv[cb] = bias[cb * 16 + l15];

#pragma unroll
    for (int rb = 0; rb < 2; rb++) {
#pragma unroll
        for (int v = 0; v < 4; v++) {
            float x[8];
            float m = -1e30f;
#pragma unroll
            for (int cb = 0; cb < 8; cb++) {
                float t = acc[rb][cb][v] + bv[cb];
                t = fmaxf(t, 0.f);
                x[cb] = t;
                m = fmaxf(m, t);
            }
#pragma unroll
            for (int off = 1; off < 16; off <<= 1) m = fmaxf(m, __shfl_xor(m, off, 64));
            float s = 0.f;
#pragma unroll
            for (int cb = 0; cb < 8; cb++) { x[cb] = __expf(x[cb] - m); s += x[cb]; }
#pragma unroll
            for (int off = 1; off < 16; off <<= 1) s += __shfl_xor(s, off, 64);
            float inv = 1.0f / s;
            int row = tile_m + wave * 32 + rb * 16 + quad * 4 + v;
#pragma unroll
            for (int cb = 0; cb < 8; cb++)
                assign_out[(size_t)row * KC + cb * 16 + l15] = f2bf(x[cb] * inv);
        }
    }
}

// ---------------- out = per-graph assign @ fea  (bf16 MFMA, fp32 out)
__global__ __launch_bounds__(256) void out_kernel(
    const short* __restrict__ assign_in, const short* __restrict__ feaT,
    float* __restrict__ out)
{
    __shared__ short lds_a[128 * 72];
    __shared__ short lds_b[128 * 72];
    int tid = threadIdx.x;
    int tile_m = blockIdx.x * 128;
    int g = tile_m >> 10;
    int wave = tid >> 6, lane = tid & 63;
    int l15 = lane & 15, quad = lane >> 4;

    floatx4 zz = {0.f, 0.f, 0.f, 0.f};
    floatx4 acc[2][8];
#pragma unroll
    for (int i = 0; i < 2; i++)
#pragma unroll
        for (int j = 0; j < 8; j++) acc[i][j] = zz;

    int row_s = tid >> 1;
    int c0 = (tid & 1) * 32;

    for (int kk = 0; kk < 2; kk++) {
        const short* srca = assign_in + (size_t)(tile_m + row_s) * KC + kk * 64 + c0;
        short* dsta = lds_a + row_s * 72 + c0;
#pragma unroll
        for (int i = 0; i < 32; i += 8)
            *reinterpret_cast<short8*>(dsta + i) = *reinterpret_cast<const short8*>(srca + i);
        const short* srcb = feaT + ((size_t)g * 128 + row_s) * KC + kk * 64 + c0;
        short* dstb = lds_b + row_s * 72 + c0;
#pragma unroll
        for (int i = 0; i < 32; i += 8)
            *reinterpret_cast<short8*>(dstb + i) = *reinterpret_cast<const short8*>(srcb + i);
        __syncthreads();
#pragma unroll
        for (int ks = 0; ks < 2; ks++) {
            short8 af[2];
#pragma unroll
            for (int rb = 0; rb < 2; rb++) {
                int m = wave * 32 + rb * 16 + l15;
                af[rb] = *reinterpret_cast<const short8*>(lds_a + m * 72 + ks * 32 + quad * 8);
            }
#pragma unroll
            for (int cb = 0; cb < 8; cb++) {
                int n = cb * 16 + l15;
                short8 bf = *reinterpret_cast<const short8*>(lds_b + n * 72 + ks * 32 + quad * 8);
                acc[0][cb] = __builtin_amdgcn_mfma_f32_16x16x32_bf16(af[0], bf, acc[0][cb], 0, 0, 0);
                acc[1][cb] = __builtin_amdgcn_mfma_f32_16x16x32_bf16(af[1], bf, acc[1][cb], 0, 0, 0);
            }
        }
        __syncthreads();
    }

#pragma unroll
    for (int rb = 0; rb < 2; rb++)
#pragma unroll
        for (int v = 0; v < 4; v++) {
            int row = tile_m + wave * 32 + rb * 16 + quad * 4 + v;
#pragma unroll
            for (int cb = 0; cb < 8; cb++)
                out[(size_t)row * DOUT + cb * 16 + l15] = acc[rb][cb][v];
        }
}

extern "C" void kernel_launch(void* const* d_in, const int* in_sizes, int n_in,
                              void* d_out, int out_size, void* d_ws, size_t ws_size,
                              hipStream_t stream) {
    const float* h      = (const float*)d_in[0];
    const float* fea    = (const float*)d_in[1];
    const float* Wself  = (const float*)d_in[2];
    const float* Wneigh = (const float*)d_in[3];
    const float* bias   = (const float*)d_in[4];
    const int*   esrc   = (const int*)d_in[5];
    const int*   edst   = (const int*)d_in[6];
    float* out = (float*)d_out;

    char* ws = (char*)d_ws;
    short* neigh  = (short*)ws;                                   // 16 MB bf16 (pre-divided)
    size_t off = (size_t)N_NODES * DIN * sizeof(short);
    short* assign = (short*)(ws + off);  off += (size_t)N_NODES * KC * sizeof(short); // 16 MB
    short* wt     = (short*)(ws + off);  off += (size_t)128 * 256 * sizeof(short);    // 64 KB
    short* feaT   = (short*)(ws + off);  off += (size_t)B_G * 128 * 128 * sizeof(short); // 2 MB
    int*   pack   = (int*)(ws + off);    off += (size_t)E_EDGES * sizeof(int);        // 4 MB
    unsigned short* csr = (unsigned short*)(ws + off); off += (size_t)E_EDGES * sizeof(unsigned short); // 2 MB
    int*   offs   = (int*)(ws + off);                             // 256 KB

    int prep_total = 128 * 256 + B_G * 128 * 128 + E_EDGES;
    prep_kernel<<<(prep_total + 255) / 256, 256, 0, stream>>>(Wself, Wneigh, fea, esrc, edst, wt, feaT, pack);
    csr_kernel<<<B_G, 1024, 0, stream>>>(pack, csr, offs);
    agg_kernel<<<256 * B_G, 256, 0, stream>>>(h, csr, offs, neigh);
    assign_kernel<<<N_NODES / 128, 256, 0, stream>>>(h, neigh, wt, bias, assign);
    out_kernel<<<N_NODES / 128, 256, 0, stream>>>(assign, feaT, out);
}

// Round 4
// 188.168 us; speedup vs baseline: 6.0430x; 1.0359x over previous
//
#include <hip/hip_runtime.h>

#define N_NODES 65536
#define B_G     64
#define NPG     1024
#define KC      128
#define DIN     128
#define E_EDGES 1048576
#define EPG     16384
#define CSTRIDE (EPG + NPG)   // per-graph CSR slots (even-padded offsets)

typedef __attribute__((ext_vector_type(8))) short short8;
typedef __attribute__((ext_vector_type(4))) float floatx4;

static __device__ __forceinline__ short f2bf(float x) {
    unsigned u = __float_as_uint(x);
    unsigned r = (u + 0x7FFF + ((u >> 16) & 1)) >> 16;
    return (short)r;
}
static __device__ __forceinline__ unsigned pack2(float a, float b) {
    return (unsigned)(unsigned short)f2bf(a) | ((unsigned)(unsigned short)f2bf(b) << 16);
}

// ================ setup: blocks 0..63 build CSR (one per graph);
//                  blocks 64.. convert wt / feaT / h_bf
__global__ __launch_bounds__(256) void setup_kernel(
    const float* __restrict__ Wself, const float* __restrict__ Wneigh,
    const float* __restrict__ fea, const float* __restrict__ h,
    const int* __restrict__ esrc, const int* __restrict__ edst,
    short* __restrict__ wt, short* __restrict__ feaT, short* __restrict__ h_bf,
    unsigned short* __restrict__ csr, int* __restrict__ offs, int* __restrict__ deg)
{
    int bid = blockIdx.x;
    int tid = threadIdx.x;
    if (bid < B_G) {
        __shared__ int cnt[NPG];
        __shared__ int ofl[NPG];
        __shared__ int ssc[256];
        int g = bid;
        int gbase = g * NPG;
        for (int i = tid; i < NPG; i += 256) cnt[i] = 0;
        __syncthreads();
        const int* ed = edst + (size_t)g * EPG;
        const int* es = esrc + (size_t)g * EPG;
        for (int it = 0; it < EPG / 256; it++)
            atomicAdd(&cnt[ed[it * 256 + tid] - gbase], 1);
        __syncthreads();
        // per-thread 4 bins, even-padded counts; block scan of 256 partials
        int b[4], p[4];
        int lsum = 0;
#pragma unroll
        for (int i = 0; i < 4; i++) {
            b[i] = cnt[4 * tid + i];
            p[i] = (b[i] + 1) & ~1;
            lsum += p[i];
        }
        ssc[tid] = lsum;
        __syncthreads();
        for (int off = 1; off < 256; off <<= 1) {
            int v = ssc[tid];
            int vv = (tid >= off) ? ssc[tid - off] : 0;
            __syncthreads();
            ssc[tid] = v + vv;
            __syncthreads();
        }
        int base = ssc[tid] - lsum;   // exclusive over padded counts
#pragma unroll
        for (int i = 0; i < 4; i++) {
            ofl[4 * tid + i] = base;
            offs[gbase + 4 * tid + i] = base;
            deg[gbase + 4 * tid + i] = b[i];
            base += p[i];
        }
        __syncthreads();
        unsigned short* cg = csr + (size_t)g * CSTRIDE;
        for (int it = 0; it < EPG / 256; it++) {
            int e = it * 256 + tid;
            int d = ed[e] - gbase;
            int s = es[e] - gbase;
            int pos = atomicAdd(&ofl[d], 1);
            cg[pos] = (unsigned short)s;
        }
    } else {
        long idx = (long)(bid - B_G) * 256 + tid;
        if (idx < 32768) {
            int n = (int)(idx >> 8), k = (int)(idx & 255);
            float v = (k < 128) ? Wself[k * 128 + n] : Wneigh[(k - 128) * 128 + n];
            wt[idx] = f2bf(v);
        } else if (idx < 32768 + 1048576) {
            long fi = idx - 32768;
            int g = (int)(fi >> 14), d = (int)((fi >> 7) & 127), k = (int)(fi & 127);
            feaT[fi] = f2bf(fea[((long)g * 128 + k) * 128 + d]);
        } else {
            long gi = idx - 32768 - 1048576;   // 8 floats per item
            const float4* hp = (const float4*)h + gi * 2;
            float4 a = hp[0], b4 = hp[1];
            uint4 w;
            w.x = pack2(a.x, a.y);
            w.y = pack2(a.z, a.w);
            w.z = pack2(b4.x, b4.y);
            w.w = pack2(b4.z, b4.w);
            ((uint4*)h_bf)[gi] = w;
        }
    }
}

// ================ aggregation (pull, bf16): one wave per node,
// 2 edges per gather instruction (lanes 0-31 edge A, 32-63 edge B)
__global__ __launch_bounds__(256) void agg_kernel(
    const short* __restrict__ h_bf, const unsigned short* __restrict__ csr,
    const int* __restrict__ offs, const int* __restrict__ deg,
    short* __restrict__ neigh)
{
    int g = blockIdx.x & 63;
    int chunk = blockIdx.x >> 6;
    int wave = threadIdx.x >> 6, lane = threadIdx.x & 63;
    int local = chunk * 4 + wave;
    int node = g * NPG + local;
    int start = offs[node];
    int m = deg[node];
    const unsigned short* lst = csr + (size_t)g * CSTRIDE + start;
    const uint2* rows = (const uint2*)h_bf + (size_t)g * NPG * 32;  // 32 uint2 / row
    int l31 = lane & 31;
    int hi = lane >> 5;
    float s0 = 0.f, s1 = 0.f, s2 = 0.f, s3 = 0.f;
    int pairs = m >> 1;
    int p = 0;
    for (; p + 4 <= pairs; p += 4) {
        unsigned pp[4];
#pragma unroll
        for (int u = 0; u < 4; u++) pp[u] = *(const unsigned*)(lst + 2 * (p + u));
        uint2 v[4];
#pragma unroll
        for (int u = 0; u < 4; u++) {
            int s = hi ? (int)(pp[u] >> 16) : (int)(pp[u] & 0xffff);
            v[u] = rows[s * 32 + l31];
        }
#pragma unroll
        for (int u = 0; u < 4; u++) {
            s0 += __uint_as_float(v[u].x << 16);
            s1 += __uint_as_float(v[u].x & 0xffff0000u);
            s2 += __uint_as_float(v[u].y << 16);
            s3 += __uint_as_float(v[u].y & 0xffff0000u);
        }
    }
    for (; p < pairs; p++) {
        unsigned pp = *(const unsigned*)(lst + 2 * p);
        int s = hi ? (int)(pp >> 16) : (int)(pp & 0xffff);
        uint2 vv = rows[s * 32 + l31];
        s0 += __uint_as_float(vv.x << 16);
        s1 += __uint_as_float(vv.x & 0xffff0000u);
        s2 += __uint_as_float(vv.y << 16);
        s3 += __uint_as_float(vv.y & 0xffff0000u);
    }
    if (m & 1) {
        int s = lst[m - 1];
        if (!hi) {
            uint2 vv = rows[s * 32 + l31];
            s0 += __uint_as_float(vv.x << 16);
            s1 += __uint_as_float(vv.x & 0xffff0000u);
            s2 += __uint_as_float(vv.y << 16);
            s3 += __uint_as_float(vv.y & 0xffff0000u);
        }
    }
    s0 += __shfl_xor(s0, 32, 64);
    s1 += __shfl_xor(s1, 32, 64);
    s2 += __shfl_xor(s2, 32, 64);
    s3 += __shfl_xor(s3, 32, 64);
    if (!hi) {
        float invd = 1.0f / fmaxf((float)m, 1.0f);
        uint2 w;
        w.x = pack2(s0 * invd, s1 * invd);
        w.y = pack2(s2 * invd, s3 * invd);
        ((uint2*)neigh)[(size_t)node * 32 + l31] = w;
    }
}

// ================ fused: assign = softmax(relu([h_bf|neigh] @ wt^T + b));
//                  out = assign @ fea   (P kept on-chip via LDS round-trip)
__global__ __launch_bounds__(256) void fused_kernel(
    const short* __restrict__ h_bf, const short* __restrict__ neigh,
    const short* __restrict__ wt, const float* __restrict__ bias,
    const short* __restrict__ feaT, float* __restrict__ out)
{
    __shared__ __align__(16) char smem[50688];
    short* lds_a = (short*)smem;            // phase1: 128x72
    short* lds_b = lds_a + 128 * 72;        // phase1: 128x72
    short* ldsP  = (short*)smem;            // phase2: 128x132 (overlaps phase1)
    short* ldsB2 = ldsP + 128 * 132;        // phase2: 64x132

    int tid = threadIdx.x;
    int tile_m = blockIdx.x * 128;
    int g = tile_m >> 10;
    int wave = tid >> 6, lane = tid & 63;
    int l15 = lane & 15, quad = lane >> 4;

    floatx4 zz = {0.f, 0.f, 0.f, 0.f};
    floatx4 acc[2][8];
#pragma unroll
    for (int i = 0; i < 2; i++)
#pragma unroll
        for (int j = 0; j < 8; j++) acc[i][j] = zz;

    int row_s = tid >> 1;
    int c0 = (tid & 1) * 32;

    // ---- GEMM1: logits = [h_bf | neigh] @ wt^T, K=256 in 4 chunks of 64
    for (int kk = 0; kk < 4; kk++) {
        const short* src = (kk < 2)
            ? h_bf + (size_t)(tile_m + row_s) * DIN + kk * 64 + c0
            : neigh + (size_t)(tile_m + row_s) * DIN + (kk - 2) * 64 + c0;
        short* dsta = lds_a + row_s * 72 + c0;
#pragma unroll
        for (int i = 0; i < 32; i += 8)
            *reinterpret_cast<short8*>(dsta + i) = *reinterpret_cast<const short8*>(src + i);
        const short* srcb = wt + row_s * 256 + kk * 64 + c0;
        short* dstb = lds_b + row_s * 72 + c0;
#pragma unroll
        for (int i = 0; i < 32; i += 8)
            *reinterpret_cast<short8*>(dstb + i) = *reinterpret_cast<const short8*>(srcb + i);
        __syncthreads();
#pragma unroll
        for (int ks = 0; ks < 2; ks++) {
            short8 af[2];
#pragma unroll
            for (int rb = 0; rb < 2; rb++) {
                int m = wave * 32 + rb * 16 + l15;
                af[rb] = *reinterpret_cast<const short8*>(lds_a + m * 72 + ks * 32 + quad * 8);
            }
#pragma unroll
            for (int cb = 0; cb < 8; cb++) {
                int n = cb * 16 + l15;
                short8 bf = *reinterpret_cast<const short8*>(lds_b + n * 72 + ks * 32 + quad * 8);
                acc[0][cb] = __builtin_amdgcn_mfma_f32_16x16x32_bf16(af[0], bf, acc[0][cb], 0, 0, 0);
                acc[1][cb] = __builtin_amdgcn_mfma_f32_16x16x32_bf16(af[1], bf, acc[1][cb], 0, 0, 0);
            }
        }
        __syncthreads();
    }

    // ---- softmax(relu(+bias)) in regs; P -> LDS (bf16, stride 132)
    float bv[8];
#pragma unroll
    for (int cb = 0; cb < 8; cb++) bv[cb] = bias[cb * 16 + l15];

#pragma unroll
    for (int rb = 0; rb < 2; rb++) {
#pragma unroll
        for (int v = 0; v < 4; v++) {
            float x[8];
            float m = -1e30f;
#pragma unroll
            for (int cb = 0; cb < 8; cb++) {
                float t = acc[rb][cb][v] + bv[cb];
                t = fmaxf(t, 0.f);
                x[cb] = t;
                m = fmaxf(m, t);
            }
#pragma unroll
            for (int off = 1; off < 16; off <<= 1) m = fmaxf(m, __shfl_xor(m, off, 64));
            float s = 0.f;
#pragma unroll
            for (int cb = 0; cb < 8; cb++) { x[cb] = __expf(x[cb] - m); s += x[cb]; }
#pragma unroll
            for (int off = 1; off < 16; off <<= 1) s += __shfl_xor(s, off, 64);
            float inv = 1.0f / s;
            int row = wave * 32 + rb * 16 + quad * 4 + v;   // local row
#pragma unroll
            for (int cb = 0; cb < 8; cb++)
                ldsP[row * 132 + cb * 16 + l15] = f2bf(x[cb] * inv);
        }
    }

    // ---- GEMM2: out = P @ fea[g], feaT staged in two 64-row halves
    floatx4 oacc[2][8];
#pragma unroll
    for (int i = 0; i < 2; i++)
#pragma unroll
        for (int j = 0; j < 8; j++) oacc[i][j] = zz;

    int r2 = tid >> 2;            // 0..63
    int c2 = (tid & 3) * 32;      // 0..96
    short8 pf[2][4];

    for (int half = 0; half < 2; half++) {
        if (half) __syncthreads();   // protect previous-half B reads
        const short* srcb = feaT + ((size_t)g * 128 + half * 64 + r2) * 128 + c2;
        short* dstb = ldsB2 + r2 * 132 + c2;
#pragma unroll
        for (int i = 0; i < 32; i += 8)
            *reinterpret_cast<short8*>(dstb + i) = *reinterpret_cast<const short8*>(srcb + i);
        __syncthreads();
        if (half == 0) {
#pragma unroll
            for (int rb = 0; rb < 2; rb++)
#pragma unroll
                for (int ks = 0; ks < 4; ks++)
                    pf[rb][ks] = *reinterpret_cast<const short8*>(
                        ldsP + (wave * 32 + rb * 16 + l15) * 132 + ks * 32 + quad * 8);
        }
#pragma unroll
        for (int cb2 = 0; cb2 < 4; cb2++) {
            int cb = half * 4 + cb2;
#pragma unroll
            for (int ks = 0; ks < 4; ks++) {
                short8 bf = *reinterpret_cast<const short8*>(
                    ldsB2 + (cb2 * 16 + l15) * 132 + ks * 32 + quad * 8);
                oacc[0][cb] = __builtin_amdgcn_mfma_f32_16x16x32_bf16(pf[0][ks], bf, oacc[0][cb], 0, 0, 0);
                oacc[1][cb] = __builtin_amdgcn_mfma_f32_16x16x32_bf16(pf[1][ks], bf, oacc[1][cb], 0, 0, 0);
            }
        }
    }

#pragma unroll
    for (int rb = 0; rb < 2; rb++)
#pragma unroll
        for (int v = 0; v < 4; v++) {
            int row = tile_m + wave * 32 + rb * 16 + quad * 4 + v;
#pragma unroll
            for (int cb = 0; cb < 8; cb++)
                out[(size_t)row * 128 + cb * 16 + l15] = oacc[rb][cb][v];
        }
}

extern "C" void kernel_launch(void* const* d_in, const int* in_sizes, int n_in,
                              void* d_out, int out_size, void* d_ws, size_t ws_size,
                              hipStream_t stream) {
    const float* h      = (const float*)d_in[0];
    const float* fea    = (const float*)d_in[1];
    const float* Wself  = (const float*)d_in[2];
    const float* Wneigh = (const float*)d_in[3];
    const float* bias   = (const float*)d_in[4];
    const int*   esrc   = (const int*)d_in[5];
    const int*   edst   = (const int*)d_in[6];
    float* out = (float*)d_out;

    char* ws = (char*)d_ws;
    short* h_bf = (short*)ws;
    size_t off = (size_t)N_NODES * DIN * sizeof(short);                       // 16 MB
    short* neigh = (short*)(ws + off); off += (size_t)N_NODES * DIN * sizeof(short);   // 16 MB
    short* wt    = (short*)(ws + off); off += (size_t)128 * 256 * sizeof(short);       // 64 KB
    short* feaT  = (short*)(ws + off); off += (size_t)B_G * 128 * 128 * sizeof(short); // 2 MB
    unsigned short* csr = (unsigned short*)(ws + off); off += (size_t)B_G * CSTRIDE * sizeof(short); // 2.2 MB
    int* offs = (int*)(ws + off); off += (size_t)N_NODES * sizeof(int);       // 256 KB
    int* deg  = (int*)(ws + off);                                             // 256 KB

    // setup grid: 64 CSR blocks + (32768 + 1048576 + 1048576)/256 = 8320 conv blocks
    setup_kernel<<<64 + 8320, 256, 0, stream>>>(Wself, Wneigh, fea, h, esrc, edst,
                                                wt, feaT, h_bf, csr, offs, deg);
    agg_kernel<<<256 * B_G, 256, 0, stream>>>(h_bf, csr, offs, deg, neigh);
    fused_kernel<<<N_NODES / 128, 256, 0, stream>>>(h_bf, neigh, wt, bias, feaT, out);
}

// Round 5
// 175.593 us; speedup vs baseline: 6.4758x; 1.0716x over previous
//
#include <hip/hip_runtime.h>

#define N_NODES 65536
#define B_G     64
#define NPG     1024
#define KC      128
#define DIN     128
#define E_EDGES 1048576
#define EPG     16384
#define NSLICE  8
#define SLICE_E (EPG / NSLICE)    // 2048 edges per slice
#define CSTRIDE (EPG + NPG)       // per-graph CSR slots (even-padded offsets)

typedef __attribute__((ext_vector_type(8))) short short8;
typedef __attribute__((ext_vector_type(4))) float floatx4;

static __device__ __forceinline__ short f2bf(float x) {
    unsigned u = __float_as_uint(x);
    unsigned r = (u + 0x7FFF + ((u >> 16) & 1)) >> 16;
    return (short)r;
}
static __device__ __forceinline__ unsigned pack2(float a, float b) {
    return (unsigned)(unsigned short)f2bf(a) | ((unsigned)(unsigned short)f2bf(b) << 16);
}

// ================ setup_a: blocks 0..511 = per-(graph,slice) degree histogram;
//                  blocks 512.. = wt / feaT / h_bf conversions
__global__ __launch_bounds__(256) void setup_a(
    const float* __restrict__ Wself, const float* __restrict__ Wneigh,
    const float* __restrict__ fea, const float* __restrict__ h,
    const int* __restrict__ edst,
    short* __restrict__ wt, short* __restrict__ feaT, short* __restrict__ h_bf,
    int* __restrict__ slicecnt)
{
    int bid = blockIdx.x;
    int tid = threadIdx.x;
    if (bid < B_G * NSLICE) {
        __shared__ int cnt[NPG];
        int g = bid >> 3, s = bid & 7;
        int gbase = g << 10;
        for (int i = tid; i < NPG; i += 256) cnt[i] = 0;
        __syncthreads();
        const int* ed = edst + (size_t)g * EPG + s * SLICE_E;
#pragma unroll
        for (int it = 0; it < SLICE_E / 256; it++)
            atomicAdd(&cnt[ed[it * 256 + tid] - gbase], 1);
        __syncthreads();
        int* sc = slicecnt + ((size_t)bid << 10);
        for (int i = tid; i < NPG; i += 256) sc[i] = cnt[i];
    } else {
        long idx = (long)(bid - B_G * NSLICE) * 256 + tid;
        if (idx < 32768) {
            int n = (int)(idx >> 8), k = (int)(idx & 255);
            float v = (k < 128) ? Wself[k * 128 + n] : Wneigh[(k - 128) * 128 + n];
            wt[idx] = f2bf(v);
        } else if (idx < 32768 + 1048576) {
            long fi = idx - 32768;
            int g = (int)(fi >> 14), d = (int)((fi >> 7) & 127), k = (int)(fi & 127);
            feaT[fi] = f2bf(fea[((long)g * 128 + k) * 128 + d]);
        } else {
            long gi = idx - 32768 - 1048576;   // 8 floats per item
            const float4* hp = (const float4*)h + gi * 2;
            float4 a = hp[0], b4 = hp[1];
            uint4 w;
            w.x = pack2(a.x, a.y);
            w.y = pack2(a.z, a.w);
            w.z = pack2(b4.x, b4.y);
            w.w = pack2(b4.z, b4.w);
            ((uint4*)h_bf)[gi] = w;
        }
    }
}

// ================ setup_b: per-graph scan -> offs, deg, per-slice bases
__global__ __launch_bounds__(1024) void setup_b(
    const int* __restrict__ slicecnt, int* __restrict__ offs,
    int* __restrict__ deg, int* __restrict__ sliceoffs)
{
    __shared__ int sa[NPG];
    int g = blockIdx.x;
    int tid = threadIdx.x;
    int s8[NSLICE];
    int d = 0;
#pragma unroll
    for (int s = 0; s < NSLICE; s++) {
        s8[s] = slicecnt[(((size_t)g * NSLICE + s) << 10) + tid];
        d += s8[s];
    }
    int p = (d + 1) & ~1;
    sa[tid] = p;
    __syncthreads();
    for (int off = 1; off < NPG; off <<= 1) {
        int v = sa[tid];
        int vv = (tid >= off) ? sa[tid - off] : 0;
        __syncthreads();
        sa[tid] = v + vv;
        __syncthreads();
    }
    int excl = sa[tid] - p;
    offs[(g << 10) + tid] = excl;
    deg[(g << 10) + tid] = d;
    int run = excl;
#pragma unroll
    for (int s = 0; s < NSLICE; s++) {
        sliceoffs[(((size_t)g * NSLICE + s) << 10) + tid] = run;
        run += s8[s];
    }
}

// ================ setup_c: per-(graph,slice) scatter into CSR
__global__ __launch_bounds__(256) void setup_c(
    const int* __restrict__ esrc, const int* __restrict__ edst,
    const int* __restrict__ sliceoffs, unsigned short* __restrict__ csr)
{
    __shared__ int cur[NPG];
    int bid = blockIdx.x;
    int tid = threadIdx.x;
    int g = bid >> 3, s = bid & 7;
    int gbase = g << 10;
    const int* so = sliceoffs + ((size_t)bid << 10);
    for (int i = tid; i < NPG; i += 256) cur[i] = so[i];
    __syncthreads();
    const int* ed = edst + (size_t)g * EPG + s * SLICE_E;
    const int* es = esrc + (size_t)g * EPG + s * SLICE_E;
    unsigned short* cg = csr + (size_t)g * CSTRIDE;
#pragma unroll
    for (int it = 0; it < SLICE_E / 256; it++) {
        int e = it * 256 + tid;
        int d = ed[e] - gbase;
        int src = es[e] - gbase;
        int pos = atomicAdd(&cur[d], 1);
        cg[pos] = (unsigned short)src;
    }
}

// ================ aggregation (pull, bf16): one wave per node,
// 2 edges per gather instruction (lanes 0-31 edge A, 32-63 edge B)
__global__ __launch_bounds__(256) void agg_kernel(
    const short* __restrict__ h_bf, const unsigned short* __restrict__ csr,
    const int* __restrict__ offs, const int* __restrict__ deg,
    short* __restrict__ neigh)
{
    int g = blockIdx.x & 63;
    int chunk = blockIdx.x >> 6;
    int wave = threadIdx.x >> 6, lane = threadIdx.x & 63;
    int local = chunk * 4 + wave;
    int node = g * NPG + local;
    int start = offs[node];
    int m = deg[node];
    const unsigned short* lst = csr + (size_t)g * CSTRIDE + start;
    const uint2* rows = (const uint2*)h_bf + (size_t)g * NPG * 32;  // 32 uint2 / row
    int l31 = lane & 31;
    int hi = lane >> 5;
    float s0 = 0.f, s1 = 0.f, s2 = 0.f, s3 = 0.f;
    int pairs = m >> 1;
    int p = 0;
    for (; p + 4 <= pairs; p += 4) {
        unsigned pp[4];
#pragma unroll
        for (int u = 0; u < 4; u++) pp[u] = *(const unsigned*)(lst + 2 * (p + u));
        uint2 v[4];
#pragma unroll
        for (int u = 0; u < 4; u++) {
            int s = hi ? (int)(pp[u] >> 16) : (int)(pp[u] & 0xffff);
            v[u] = rows[s * 32 + l31];
        }
#pragma unroll
        for (int u = 0; u < 4; u++) {
            s0 += __uint_as_float(v[u].x << 16);
            s1 += __uint_as_float(v[u].x & 0xffff0000u);
            s2 += __uint_as_float(v[u].y << 16);
            s3 += __uint_as_float(v[u].y & 0xffff0000u);
        }
    }
    for (; p < pairs; p++) {
        unsigned pp = *(const unsigned*)(lst + 2 * p);
        int s = hi ? (int)(pp >> 16) : (int)(pp & 0xffff);
        uint2 vv = rows[s * 32 + l31];
        s0 += __uint_as_float(vv.x << 16);
        s1 += __uint_as_float(vv.x & 0xffff0000u);
        s2 += __uint_as_float(vv.y << 16);
        s3 += __uint_as_float(vv.y & 0xffff0000u);
    }
    if (m & 1) {
        int s = lst[m - 1];
        if (!hi) {
            uint2 vv = rows[s * 32 + l31];
            s0 += __uint_as_float(vv.x << 16);
            s1 += __uint_as_float(vv.x & 0xffff0000u);
            s2 += __uint_as_float(vv.y << 16);
            s3 += __uint_as_float(vv.y & 0xffff0000u);
        }
    }
    s0 += __shfl_xor(s0, 32, 64);
    s1 += __shfl_xor(s1, 32, 64);
    s2 += __shfl_xor(s2, 32, 64);
    s3 += __shfl_xor(s3, 32, 64);
    if (!hi) {
        float invd = 1.0f / fmaxf((float)m, 1.0f);
        uint2 w;
        w.x = pack2(s0 * invd, s1 * invd);
        w.y = pack2(s2 * invd, s3 * invd);
        ((uint2*)neigh)[(size_t)node * 32 + l31] = w;
    }
}

// ================ fused: assign = softmax(relu([h_bf|neigh] @ wt^T + b));
//                  out = assign @ fea   (P kept on-chip via LDS round-trip)
__global__ __launch_bounds__(256) void fused_kernel(
    const short* __restrict__ h_bf, const short* __restrict__ neigh,
    const short* __restrict__ wt, const float* __restrict__ bias,
    const short* __restrict__ feaT, float* __restrict__ out)
{
    __shared__ __align__(16) char smem[50688];
    short* lds_a = (short*)smem;            // phase1: 128x72
    short* lds_b = lds_a + 128 * 72;        // phase1: 128x72
    short* ldsP  = (short*)smem;            // phase2: 128x132 (overlaps phase1)
    short* ldsB2 = ldsP + 128 * 132;        // phase2: 64x132

    int tid = threadIdx.x;
    int tile_m = blockIdx.x * 128;
    int g = tile_m >> 10;
    int wave = tid >> 6, lane = tid & 63;
    int l15 = lane & 15, quad = lane >> 4;

    floatx4 zz = {0.f, 0.f, 0.f, 0.f};
    floatx4 acc[2][8];
#pragma unroll
    for (int i = 0; i < 2; i++)
#pragma unroll
        for (int j = 0; j < 8; j++) acc[i][j] = zz;

    int row_s = tid >> 1;
    int c0 = (tid & 1) * 32;

    // ---- GEMM1: logits = [h_bf | neigh] @ wt^T, K=256 in 4 chunks of 64
    for (int kk = 0; kk < 4; kk++) {
        const short* src = (kk < 2)
            ? h_bf + (size_t)(tile_m + row_s) * DIN + kk * 64 + c0
            : neigh + (size_t)(tile_m + row_s) * DIN + (kk - 2) * 64 + c0;
        short* dsta = lds_a + row_s * 72 + c0;
#pragma unroll
        for (int i = 0; i < 32; i += 8)
            *reinterpret_cast<short8*>(dsta + i) = *reinterpret_cast<const short8*>(src + i);
        const short* srcb = wt + row_s * 256 + kk * 64 + c0;
        short* dstb = lds_b + row_s * 72 + c0;
#pragma unroll
        for (int i = 0; i < 32; i += 8)
            *reinterpret_cast<short8*>(dstb + i) = *reinterpret_cast<const short8*>(srcb + i);
        __syncthreads();
#pragma unroll
        for (int ks = 0; ks < 2; ks++) {
            short8 af[2];
#pragma unroll
            for (int rb = 0; rb < 2; rb++) {
                int m = wave * 32 + rb * 16 + l15;
                af[rb] = *reinterpret_cast<const short8*>(lds_a + m * 72 + ks * 32 + quad * 8);
            }
#pragma unroll
            for (int cb = 0; cb < 8; cb++) {
                int n = cb * 16 + l15;
                short8 bf = *reinterpret_cast<const short8*>(lds_b + n * 72 + ks * 32 + quad * 8);
                acc[0][cb] = __builtin_amdgcn_mfma_f32_16x16x32_bf16(af[0], bf, acc[0][cb], 0, 0, 0);
                acc[1][cb] = __builtin_amdgcn_mfma_f32_16x16x32_bf16(af[1], bf, acc[1][cb], 0, 0, 0);
            }
        }
        __syncthreads();
    }

    // ---- softmax(relu(+bias)) in regs; P -> LDS (bf16, stride 132)
    float bv[8];
#pragma unroll
    for (int cb = 0; cb < 8; cb++) bv[cb] = bias[cb * 16 + l15];

#pragma unroll
    for (int rb = 0; rb < 2; rb++) {
#pragma unroll
        for (int v = 0; v < 4; v++) {
            float x[8];
            float m = -1e30f;
#pragma unroll
            for (int cb = 0; cb < 8; cb++) {
                float t = acc[rb][cb][v] + bv[cb];
                t = fmaxf(t, 0.f);
                x[cb] = t;
                m = fmaxf(m, t);
            }
#pragma unroll
            for (int off = 1; off < 16; off <<= 1) m = fmaxf(m, __shfl_xor(m, off, 64));
            float s = 0.f;
#pragma unroll
            for (int cb = 0; cb < 8; cb++) { x[cb] = __expf(x[cb] - m); s += x[cb]; }
#pragma unroll
            for (int off = 1; off < 16; off <<= 1) s += __shfl_xor(s, off, 64);
            float inv = 1.0f / s;
            int row = wave * 32 + rb * 16 + quad * 4 + v;   // local row
#pragma unroll
            for (int cb = 0; cb < 8; cb++)
                ldsP[row * 132 + cb * 16 + l15] = f2bf(x[cb] * inv);
        }
    }

    // ---- GEMM2: out = P @ fea[g], feaT staged in two 64-row halves
    floatx4 oacc[2][8];
#pragma unroll
    for (int i = 0; i < 2; i++)
#pragma unroll
        for (int j = 0; j < 8; j++) oacc[i][j] = zz;

    int r2 = tid >> 2;            // 0..63
    int c2 = (tid & 3) * 32;      // 0..96
    short8 pf[2][4];

    for (int half = 0; half < 2; half++) {
        if (half) __syncthreads();   // protect previous-half B reads
        const short* srcb = feaT + ((size_t)g * 128 + half * 64 + r2) * 128 + c2;
        short* dstb = ldsB2 + r2 * 132 + c2;
#pragma unroll
        for (int i = 0; i < 32; i += 8)
            *reinterpret_cast<short8*>(dstb + i) = *reinterpret_cast<const short8*>(srcb + i);
        __syncthreads();
        if (half == 0) {
#pragma unroll
            for (int rb = 0; rb < 2; rb++)
#pragma unroll
                for (int ks = 0; ks < 4; ks++)
                    pf[rb][ks] = *reinterpret_cast<const short8*>(
                        ldsP + (wave * 32 + rb * 16 + l15) * 132 + ks * 32 + quad * 8);
        }
#pragma unroll
        for (int cb2 = 0; cb2 < 4; cb2++) {
            int cb = half * 4 + cb2;
#pragma unroll
            for (int ks = 0; ks < 4; ks++) {
                short8 bf = *reinterpret_cast<const short8*>(
                    ldsB2 + (cb2 * 16 + l15) * 132 + ks * 32 + quad * 8);
                oacc[0][cb] = __builtin_amdgcn_mfma_f32_16x16x32_bf16(pf[0][ks], bf, oacc[0][cb], 0, 0, 0);
                oacc[1][cb] = __builtin_amdgcn_mfma_f32_16x16x32_bf16(pf[1][ks], bf, oacc[1][cb], 0, 0, 0);
            }
        }
    }

#pragma unroll
    for (int rb = 0; rb < 2; rb++)
#pragma unroll
        for (int v = 0; v < 4; v++) {
            int row = tile_m + wave * 32 + rb * 16 + quad * 4 + v;
#pragma unroll
            for (int cb = 0; cb < 8; cb++)
                out[(size_t)row * 128 + cb * 16 + l15] = oacc[rb][cb][v];
        }
}

extern "C" void kernel_launch(void* const* d_in, const int* in_sizes, int n_in,
                              void* d_out, int out_size, void* d_ws, size_t ws_size,
                              hipStream_t stream) {
    const float* h      = (const float*)d_in[0];
    const float* fea    = (const float*)d_in[1];
    const float* Wself  = (const float*)d_in[2];
    const float* Wneigh = (const float*)d_in[3];
    const float* bias   = (const float*)d_in[4];
    const int*   esrc   = (const int*)d_in[5];
    const int*   edst   = (const int*)d_in[6];
    float* out = (float*)d_out;

    char* ws = (char*)d_ws;
    short* h_bf = (short*)ws;
    size_t off = (size_t)N_NODES * DIN * sizeof(short);                       // 16 MB
    short* neigh = (short*)(ws + off); off += (size_t)N_NODES * DIN * sizeof(short);   // 16 MB
    short* wt    = (short*)(ws + off); off += (size_t)128 * 256 * sizeof(short);       // 64 KB
    short* feaT  = (short*)(ws + off); off += (size_t)B_G * 128 * 128 * sizeof(short); // 2 MB
    unsigned short* csr = (unsigned short*)(ws + off); off += (size_t)B_G * CSTRIDE * sizeof(short); // 2.2 MB
    int* offs = (int*)(ws + off); off += (size_t)N_NODES * sizeof(int);       // 256 KB
    int* deg  = (int*)(ws + off); off += (size_t)N_NODES * sizeof(int);       // 256 KB
    int* slicecnt  = (int*)(ws + off); off += (size_t)B_G * NSLICE * NPG * sizeof(int); // 2 MB
    int* sliceoffs = (int*)(ws + off);                                        // 2 MB

    // setup_a grid: 512 hist blocks + (32768 + 1048576 + 1048576)/256 = 8320 conv blocks
    setup_a<<<B_G * NSLICE + 8320, 256, 0, stream>>>(Wself, Wneigh, fea, h, edst,
                                                     wt, feaT, h_bf, slicecnt);
    setup_b<<<B_G, 1024, 0, stream>>>(slicecnt, offs, deg, sliceoffs);
    setup_c<<<B_G * NSLICE, 256, 0, stream>>>(esrc, edst, sliceoffs, csr);
    agg_kernel<<<256 * B_G, 256, 0, stream>>>(h_bf, csr, offs, deg, neigh);
    fused_kernel<<<N_NODES / 128, 256, 0, stream>>>(h_bf, neigh, wt, bias, feaT, out);
}